// Round 16
// baseline (364.539 us; speedup 1.0000x reference)
//
#include <hip/hip_runtime.h>
#include <hip/hip_bf16.h>

#define N_NODES 100000
#define N_EDGES 3200000
#define F_IN 128
#define HID 16
#define N_CLASSES 32
#define N_RELS 20
#define BN_EPS 1e-5f
#define N_CELLS (N_NODES * N_RELS)          // 2,000,000  (REL-MAJOR: m = r*N_NODES + d)
#define BIN_SHIFT 13
#define BIN_CELLS 8192
#define NBINS ((N_CELLS + BIN_CELLS - 1) / BIN_CELLS)   // 245
#define CHUNK 8192
#define NBLK ((N_EDGES + CHUNK - 1) / CHUNK)            // 391
#define HM_N (NBINS * NBLK)                             // 95,795
#define HM_NB ((HM_N + 2047) / 2048)                    // 47
#define SLOT_ELEMS (N_NODES * HID)                      // 1,600,000 bf16 per slot
#define XPAD 136                                        // padded LDS row stride (bf16)

// ---------------- workspace layout (bytes), peak 98.1 MB ----------------
#define OFF_CS     0ull                 // int[N_CELLS]          8,000,000 (cell end-offsets)
#define OFF_REC    8000000ull           // u32[E] (src)         12,800,000 ; overlaid by buf2 after conv2_agg
#define OFF_AGG1   20800000ull          // float[N*16]           6,400,000
#define OFF_HM     27200000ull          // int[HM_N]               384,000 (rounded)
#define OFF_BSUM   27584000ull          // int[1024]                 4,096
#define OFF_BINOFF 27588096ull          // int[NBINS+1]              1,024
#define OFF_ST1    27589120ull          // float[64]                   256
#define OFF_ST2    27589376ull          // float[64]                   256
#define OFF_WT     27589632ull          // bf16[21*4*64*8] fragment-major  86,016
#define OFF_W2T    27675648ull          // bf16[11*32*32]           22,528
#define OFF_X      27698176ull          // bf16 regionX: 22 slots x [N*16] = 70,400,000 -> 98,098,176
                                        // CSR build: u32 bucket[E] (12.8 MB) overlays slots 0..3.
                                        // xform: slots 0..19 = h1; slot 20 = hbnb; slot 21 unused (finite).
                                        // conv2: agg2 view = slots 0..21; buf2 overlays rec after conv2_agg.
#define SLOT_BYTES 3200000ull           // one [N][16] bf16 slot

typedef __attribute__((ext_vector_type(8))) short bf16x8;
typedef __attribute__((ext_vector_type(4))) short bf16x4;
typedef __attribute__((ext_vector_type(2))) short bf16x2;
typedef __attribute__((ext_vector_type(4))) float f32x4;

__device__ inline short f2bf(float f) {
    union { __hip_bfloat16 h; short s; } u;
    u.h = __float2bfloat16(f);
    return u.s;
}

__device__ inline float bf2f(short s) {
    union { unsigned u; float f; } x;
    x.u = ((unsigned)(unsigned short)s) << 16;
    return x.f;
}

// ---------------- CSR build: hist2 -> scan(hm) -> binoff -> bucket2 -> place ----------------

__global__ __launch_bounds__(256) void hist2_kernel(const int* __restrict__ et,
                                                    const int* __restrict__ dst,
                                                    int* __restrict__ hm) {
    __shared__ int lh[NBINS];
    int t = threadIdx.x;
    for (int i = t; i < NBINS; i += 256) lh[i] = 0;
    __syncthreads();
    int e0 = blockIdx.x * CHUNK, e1 = min(e0 + CHUNK, N_EDGES);
    for (int e = e0 + t; e < e1; e += 256) {
        int m = et[e] * N_NODES + dst[e];
        atomicAdd(&lh[m >> BIN_SHIFT], 1);
    }
    __syncthreads();
    for (int i = t; i < NBINS; i += 256) hm[i * NBLK + blockIdx.x] = lh[i];
}

__global__ void scan_k1(const int* __restrict__ a, int* __restrict__ bsum, int n) {
    __shared__ int red[256];
    int base = blockIdx.x * 2048 + threadIdx.x * 8;
    int s = 0;
#pragma unroll
    for (int i = 0; i < 8; ++i) {
        int idx = base + i;
        if (idx < n) s += a[idx];
    }
    red[threadIdx.x] = s;
    __syncthreads();
    for (int off = 128; off > 0; off >>= 1) {
        if (threadIdx.x < off) red[threadIdx.x] += red[threadIdx.x + off];
        __syncthreads();
    }
    if (threadIdx.x == 0) bsum[blockIdx.x] = red[0];
}

__global__ void scan_k2(int* __restrict__ bsum, int nb) {
    __shared__ int p[1024];
    int t = threadIdx.x;
    int v = (t < nb) ? bsum[t] : 0;
    p[t] = v;
    __syncthreads();
    for (int off = 1; off < 1024; off <<= 1) {
        int a = (t >= off) ? p[t - off] : 0;
        __syncthreads();
        p[t] += a;
        __syncthreads();
    }
    if (t < nb) bsum[t] = p[t] - v;  // exclusive
}

__global__ void scan_k3(int* __restrict__ a, const int* __restrict__ bsum, int n) {
    __shared__ int red[256];
    int base = blockIdx.x * 2048 + threadIdx.x * 8;
    int v[8];
    int s = 0;
#pragma unroll
    for (int i = 0; i < 8; ++i) {
        int idx = base + i;
        v[i] = (idx < n) ? a[idx] : 0;
        s += v[i];
    }
    red[threadIdx.x] = s;
    __syncthreads();
    for (int off = 1; off < 256; off <<= 1) {
        int t = (threadIdx.x >= off) ? red[threadIdx.x - off] : 0;
        __syncthreads();
        red[threadIdx.x] += t;
        __syncthreads();
    }
    int run = bsum[blockIdx.x] + red[threadIdx.x] - s;  // exclusive
#pragma unroll
    for (int i = 0; i < 8; ++i) {
        int idx = base + i;
        if (idx < n) a[idx] = run;
        run += v[i];
    }
}

__global__ void binoff_kernel(const int* __restrict__ hm, int* __restrict__ binoff) {
    int t = threadIdx.x;  // 256 >= NBINS
    if (t < NBINS) binoff[t] = hm[t * NBLK];
    if (t == 0) binoff[NBINS] = N_EDGES;
}

// deterministic partition; u32 payload: (cell_within_bin << 17) | src
__global__ __launch_bounds__(256) void bucket2_kernel(const int* __restrict__ src,
                                                      const int* __restrict__ dst,
                                                      const int* __restrict__ et,
                                                      const int* __restrict__ hm,
                                                      unsigned* __restrict__ bucket) {
    __shared__ int ptr[NBINS];
    int t = threadIdx.x;
    for (int i = t; i < NBINS; i += 256) ptr[i] = hm[i * NBLK + blockIdx.x];
    __syncthreads();
    int e0 = blockIdx.x * CHUNK, e1 = min(e0 + CHUNK, N_EDGES);
    for (int e = e0 + t; e < e1; e += 256) {
        int m = et[e] * N_NODES + dst[e];
        int pos = atomicAdd(&ptr[m >> BIN_SHIFT], 1);
        bucket[pos] = ((unsigned)(m & (BIN_CELLS - 1)) << 17) | (unsigned)src[e];
    }
}

// one workgroup per bin: cell hist + scan + placement entirely in LDS
__global__ __launch_bounds__(256) void place_kernel(const unsigned* __restrict__ bucket,
                                                    const int* __restrict__ binoff,
                                                    int* __restrict__ cs,
                                                    unsigned* __restrict__ rec) {
    __shared__ int cnt[BIN_CELLS];
    __shared__ int part[256];
    int b = blockIdx.x;
    int cellbase = b << BIN_SHIFT;
    int ncells = min(BIN_CELLS, N_CELLS - cellbase);
    int ebase = binoff[b], eend = binoff[b + 1];
    int t = threadIdx.x;
    for (int i = t; i < BIN_CELLS; i += 256) cnt[i] = 0;
    __syncthreads();
    for (int e = ebase + t; e < eend; e += 256) {
        int c = (int)(bucket[e] >> 17);
        atomicAdd(&cnt[c], 1);
    }
    __syncthreads();
    int b32 = t * 32;
    int s = 0;
#pragma unroll
    for (int i = 0; i < 32; ++i) s += cnt[b32 + i];
    part[t] = s;
    __syncthreads();
    for (int off = 1; off < 256; off <<= 1) {
        int a = (t >= off) ? part[t - off] : 0;
        __syncthreads();
        part[t] += a;
        __syncthreads();
    }
    int run = (t ? part[t - 1] : 0);
#pragma unroll
    for (int i = 0; i < 32; ++i) { int c = cnt[b32 + i]; cnt[b32 + i] = run; run += c; }
    __syncthreads();
    for (int e = ebase + t; e < eend; e += 256) {
        unsigned p = bucket[e];
        int c = (int)(p >> 17);
        int pos = ebase + atomicAdd(&cnt[c], 1);
        rec[pos] = p & 0x1FFFFu;
    }
    __syncthreads();
    for (int c = t; c < ncells; c += 256) cs[cellbase + c] = ebase + cnt[c];
}

// ---------------- weight prep ----------------

// FRAGMENT-MAJOR: WtF[(r*4+s)*64 + kgrp*16 + col][8] = W_r[s*32+kgrp*8+e][col]
__global__ void wt_convert(const float* __restrict__ W1, const float* __restrict__ root1,
                           __hip_bfloat16* __restrict__ Wt) {
    int r = blockIdx.x;  // 0..20
    const float* src = (r < N_RELS) ? (W1 + (size_t)r * F_IN * HID) : root1;
    for (int i = threadIdx.x; i < F_IN * HID; i += 256) {
        int f = i >> 4, o = i & 15;
        int s = f >> 5, kgrp = (f >> 3) & 3, e = f & 7;
        size_t dst = (((size_t)(r * 4 + s) * 64) + kgrp * 16 + o) * 8 + e;
        Wt[dst] = __float2bfloat16(src[i]);
    }
}

__global__ void wt2_convert(const float* __restrict__ W2, const float* __restrict__ root2,
                            __hip_bfloat16* __restrict__ W2t) {
    int i = blockIdx.x * 256 + threadIdx.x;  // over 11*32*32
    if (i < 11 * 32 * 32) {
        int p = i >> 10, oc = (i >> 5) & 31, k = i & 31;
        float v;
        if (p == 10) v = (k < 16) ? root2[k * N_CLASSES + oc] : 0.f;
        else v = W2[((size_t)(2 * p + (k >> 4)) * HID + (k & 15)) * N_CLASSES + oc];
        W2t[i] = __float2bfloat16(v);
    }
}

// ---------------- conv1 ----------------

__global__ __launch_bounds__(256, 4) void xform_gemm(const float* __restrict__ x,
                                                     const __hip_bfloat16* __restrict__ Wt,
                                                     const float* __restrict__ b1,
                                                     __hip_bfloat16* __restrict__ h1,
                                                     float* __restrict__ agg1) {
    __shared__ __hip_bfloat16 xs[64 * XPAD];   // 17,408 B
    int t = threadIdx.x;
    int nodeBase = blockIdx.x * 64;

#pragma unroll
    for (int it = 0; it < 4; ++it) {
        int idx = it * 256 + t;
        int ln = idx >> 4;
        int g = (idx & 15) * 8;
        int node = nodeBase + ln;
        float4 a = {0.f, 0.f, 0.f, 0.f}, b = {0.f, 0.f, 0.f, 0.f};
        if (node < N_NODES) {
            const float* xp = x + (size_t)node * F_IN + g;
            a = *(const float4*)xp;
            b = *(const float4*)(xp + 4);
        }
        bf16x8 v;
        v[0] = f2bf(a.x); v[1] = f2bf(a.y); v[2] = f2bf(a.z); v[3] = f2bf(a.w);
        v[4] = f2bf(b.x); v[5] = f2bf(b.y); v[6] = f2bf(b.z); v[7] = f2bf(b.w);
        *(bf16x8*)(&xs[ln * XPAD + g]) = v;
    }
    __syncthreads();

    int lane = t & 63;
    int wave = t >> 6;
    int col = lane & 15;
    int kgrp = lane >> 4;
    int row = wave * 16 + col;
    int node = nodeBase + row;
    bool valid = node < N_NODES;

    bf16x8 xf[4];
#pragma unroll
    for (int s = 0; s < 4; ++s)
        xf[s] = *(const bf16x8*)(&xs[row * XPAD + s * 32 + kgrp * 8]);

    for (int r = 0; r < N_RELS + 1; ++r) {
        f32x4 acc = {0.f, 0.f, 0.f, 0.f};
#pragma unroll
        for (int s = 0; s < 4; ++s) {
            bf16x8 wf = *(const bf16x8*)(Wt + (((size_t)(r * 4 + s) * 64) + lane) * 8);
            acc = __builtin_amdgcn_mfma_f32_16x16x32_bf16(wf, xf[s], acc, 0, 0, 0);
        }
        if (valid) {
            if (r < N_RELS) {
                union { ushort4 u4; short s4[4]; } o;
                o.s4[0] = f2bf(acc[0]); o.s4[1] = f2bf(acc[1]);
                o.s4[2] = f2bf(acc[2]); o.s4[3] = f2bf(acc[3]);
                *(ushort4*)(h1 + ((size_t)r * N_NODES + node) * HID + kgrp * 4) = o.u4;
            } else {
                int c0 = kgrp * 4;
                float4 o = {acc[0] + b1[c0], acc[1] + b1[c0 + 1],
                            acc[2] + b1[c0 + 2], acc[3] + b1[c0 + 3]};
                *(float4*)(agg1 + (size_t)node * HID + c0) = o;
            }
        }
    }
}

// 8 lanes per dst (lane o owns features o*2..o*2+1), ALL relations in-register.
// 800K threads (12.5K waves, 1.5x oversubscribed) -> occupancy ~90%+, degree
// tail hidden. Per-edge wave traffic unchanged (8 x 4B consecutive = 32B).
// Final write: coalesced float2 non-atomic RMW on agg1 (pre-seeded root+b1).
__global__ __launch_bounds__(256) void conv1_agg(const __hip_bfloat16* __restrict__ h1,
                                                 const unsigned* __restrict__ rec,
                                                 const int* __restrict__ cs,
                                                 float* __restrict__ agg1,
                                                 float* __restrict__ st1) {
    __shared__ float ls[HID], lq[HID];
    if (threadIdx.x < HID) { ls[threadIdx.x] = 0.f; lq[threadIdx.x] = 0.f; }
    __syncthreads();
    int o = threadIdx.x & 7, slot = threadIdx.x >> 3;   // 32 dst per block
    int d = blockIdx.x * 32 + slot;
    bool valid = d < N_NODES;
    float acc[2] = {0.f, 0.f};
    if (valid) {
        for (int r = 0; r < N_RELS; ++r) {
            int m = r * N_NODES + d;
            int s0 = (m == 0) ? 0 : cs[m - 1];
            int s1 = cs[m];
            if (s1 > s0) {
                const __hip_bfloat16* hr = h1 + (size_t)r * SLOT_ELEMS + o * 2;
                float pa[2] = {0.f, 0.f};
                for (int i = s0; i < s1; ++i) {
                    int sn = rec[i];
                    bf16x2 v = *(const bf16x2*)(hr + (size_t)sn * HID);
                    pa[0] += bf2f(v[0]);
                    pa[1] += bf2f(v[1]);
                }
                float inv = 1.0f / (float)(s1 - s0);
                acc[0] = fmaf(pa[0], inv, acc[0]);
                acc[1] = fmaf(pa[1], inv, acc[1]);
            }
        }
    }
    float vout[2] = {0.f, 0.f};
    if (valid) {
        float2* ap = (float2*)(agg1 + (size_t)d * HID + o * 2);
        float2 a0 = *ap;
        vout[0] = a0.x + acc[0];
        vout[1] = a0.y + acc[1];
        *ap = float2{vout[0], vout[1]};
    }
#pragma unroll
    for (int k = 0; k < 2; ++k) {
        atomicAdd(&ls[o * 2 + k], vout[k]);
        atomicAdd(&lq[o * 2 + k], vout[k] * vout[k]);
    }
    __syncthreads();
    if (threadIdx.x < HID) {
        atomicAdd(&st1[threadIdx.x], ls[threadIdx.x]);
        atomicAdd(&st1[HID + threadIdx.x], lq[threadIdx.x]);
    }
}

// BN1 + ReLU -> bf16 into regionX slot 20
__global__ void bn_relu1(const float* __restrict__ a, const float* __restrict__ stats,
                         const float* __restrict__ gamma, const float* __restrict__ beta,
                         __hip_bfloat16* __restrict__ hb) {
    int i = blockIdx.x * 256 + threadIdx.x;
    if (i < N_NODES * HID) {
        int j = i & (HID - 1);
        float mean = stats[j] * (1.0f / N_NODES);
        float var = stats[HID + j] * (1.0f / N_NODES) - mean * mean;
        float rs = rsqrtf(var + BN_EPS);
        float val = (a[i] - mean) * rs * gamma[j] + beta[j];
        hb[i] = __float2bfloat16(fmaxf(val, 0.f));
    }
}

// ---------------- conv2 ----------------

// 2 lanes per cell, linear grid over cells; hbn (3.2 MB) L2-resident;
// bf16x8 gathers; coalesced bf16x8 mean writes; no atomics.
__global__ __launch_bounds__(256) void conv2_agg(const __hip_bfloat16* __restrict__ hbnb,
                                                 const unsigned* __restrict__ rec,
                                                 const int* __restrict__ cs,
                                                 __hip_bfloat16* __restrict__ agg2) {
    int pair = threadIdx.x >> 1, half = threadIdx.x & 1;
    int m = blockIdx.x * 128 + pair;
    if (m >= N_CELLS) return;
    int s0 = (m == 0) ? 0 : cs[m - 1];
    int s1 = cs[m];
    const __hip_bfloat16* hb = hbnb + half * 8;
    float acc[8] = {0.f, 0.f, 0.f, 0.f, 0.f, 0.f, 0.f, 0.f};
    for (int i = s0; i < s1; ++i) {
        int sn = rec[i];
        bf16x8 v = *(const bf16x8*)(hb + (size_t)sn * HID);
#pragma unroll
        for (int k = 0; k < 8; ++k) acc[k] += bf2f(v[k]);
    }
    float inv = (s1 > s0) ? 1.0f / (float)(s1 - s0) : 0.f;
    bf16x8 o;
#pragma unroll
    for (int k = 0; k < 8; ++k) o[k] = f2bf(acc[k] * inv);
    *(bf16x8*)(agg2 + (size_t)m * HID + half * 8) = o;
}

// buf2[n][c] = sum_p mfma over relation pairs (+ root2 via slot 20) + b2
__global__ __launch_bounds__(256) void gemm2(const __hip_bfloat16* __restrict__ agg2,
                                             const __hip_bfloat16* __restrict__ W2t,
                                             const float* __restrict__ b2,
                                             float* __restrict__ buf2) {
    int wave = threadIdx.x >> 6, lane = threadIdx.x & 63;
    int col = lane & 15, kgrp = lane >> 4;
    int node = blockIdx.x * 64 + wave * 16 + col;
    bool valid = node < N_NODES;
    int nidx = valid ? node : 0;

    bf16x8 bf[11];
#pragma unroll
    for (int p = 0; p < 11; ++p) {
        int slot = 2 * p + (kgrp >> 1);
        bf[p] = *(const bf16x8*)(agg2 + ((size_t)slot * N_NODES + nidx) * HID + (kgrp & 1) * 8);
    }
#pragma unroll
    for (int ct = 0; ct < 2; ++ct) {
        f32x4 acc = {0.f, 0.f, 0.f, 0.f};
#pragma unroll
        for (int p = 0; p < 11; ++p) {
            bf16x8 wf = *(const bf16x8*)(W2t + ((size_t)p * 32 + ct * 16 + col) * 32 + kgrp * 8);
            acc = __builtin_amdgcn_mfma_f32_16x16x32_bf16(wf, bf[p], acc, 0, 0, 0);
        }
        if (valid) {
            int c0 = ct * 16 + kgrp * 4;
            float4 o = {acc[0] + b2[c0], acc[1] + b2[c0 + 1],
                        acc[2] + b2[c0 + 2], acc[3] + b2[c0 + 3]};
            *(float4*)(buf2 + (size_t)node * N_CLASSES + c0) = o;
        }
    }
}

template <int CH>
__global__ void bn_stats(const float* __restrict__ v, float* __restrict__ stats) {
    __shared__ float ls[CH], lq[CH];
    if (threadIdx.x < CH) { ls[threadIdx.x] = 0.f; lq[threadIdx.x] = 0.f; }
    __syncthreads();
    const int total = N_NODES * CH;
    int j = threadIdx.x % CH;
    float s = 0.f, q = 0.f;
    for (int i = blockIdx.x * blockDim.x + threadIdx.x; i < total; i += gridDim.x * blockDim.x) {
        float t = v[i];
        s += t; q += t * t;
    }
    atomicAdd(&ls[j], s);
    atomicAdd(&lq[j], q);
    __syncthreads();
    if (threadIdx.x < CH) {
        atomicAdd(&stats[threadIdx.x], ls[threadIdx.x]);
        atomicAdd(&stats[CH + threadIdx.x], lq[threadIdx.x]);
    }
}

__global__ void final_kernel(const float* __restrict__ buf2, const float* __restrict__ stats,
                             const float* __restrict__ gamma, const float* __restrict__ beta,
                             float* __restrict__ out) {
    int idx = blockIdx.x * 256 + threadIdx.x;  // over N*32, exact
    int j = threadIdx.x & 31;
    float mean = stats[j] * (1.0f / N_NODES);
    float var = stats[N_CLASSES + j] * (1.0f / N_NODES) - mean * mean;
    float rs = rsqrtf(var + BN_EPS);
    float v = fmaxf((buf2[idx] - mean) * rs * gamma[j] + beta[j], 0.f);
    float m = v;
#pragma unroll
    for (int o = 16; o >= 1; o >>= 1) m = fmaxf(m, __shfl_xor(m, o, 32));
    float ex = __expf(v - m);
    float ssum = ex;
#pragma unroll
    for (int o = 16; o >= 1; o >>= 1) ssum += __shfl_xor(ssum, o, 32);
    out[idx] = (v - m) - logf(ssum);
}

// ---------------- launcher ----------------
extern "C" void kernel_launch(void* const* d_in, const int* in_sizes, int n_in,
                              void* d_out, int out_size, void* d_ws, size_t ws_size,
                              hipStream_t stream) {
    const float* x      = (const float*)d_in[0];
    const int*   eidx   = (const int*)d_in[1];
    const int*   etype  = (const int*)d_in[2];
    const float* W1     = (const float*)d_in[3];
    const float* root1  = (const float*)d_in[4];
    const float* b1     = (const float*)d_in[5];
    const float* gamma1 = (const float*)d_in[6];
    const float* beta1  = (const float*)d_in[7];
    const float* W2     = (const float*)d_in[8];
    const float* root2  = (const float*)d_in[9];
    const float* b2     = (const float*)d_in[10];
    const float* gamma2 = (const float*)d_in[11];
    const float* beta2  = (const float*)d_in[12];

    const int* src = eidx;
    const int* dst = eidx + N_EDGES;

    char* ws = (char*)d_ws;
    int*      cs     = (int*)(ws + OFF_CS);
    unsigned* rec    = (unsigned*)(ws + OFF_REC);
    float*    buf2   = (float*)(ws + OFF_REC);     // overlays rec (dead after conv2_agg)
    float*    agg1   = (float*)(ws + OFF_AGG1);
    int*      hm     = (int*)(ws + OFF_HM);
    int*      bsum   = (int*)(ws + OFF_BSUM);
    int*      binoff = (int*)(ws + OFF_BINOFF);
    float*    st1    = (float*)(ws + OFF_ST1);
    float*    st2    = (float*)(ws + OFF_ST2);
    __hip_bfloat16* Wt  = (__hip_bfloat16*)(ws + OFF_WT);
    __hip_bfloat16* W2t = (__hip_bfloat16*)(ws + OFF_W2T);
    unsigned* bucket = (unsigned*)(ws + OFF_X);                                // dead after place_kernel
    __hip_bfloat16* rx   = (__hip_bfloat16*)(ws + OFF_X);                      // regionX base
    __hip_bfloat16* h1   = rx;                                                 // slots 0..19
    __hip_bfloat16* hbnb = rx + (size_t)20 * SLOT_ELEMS;                       // slot 20
    __hip_bfloat16* agg2 = rx;                                                 // slots 0..21 (conv2 view)

    float* out = (float*)d_out;

    hipMemsetAsync(st1, 0, 512, stream);           // zeroes st1 (256B) + st2 (256B)

    hist2_kernel<<<NBLK, 256, 0, stream>>>(etype, dst, hm);
    scan_k1<<<HM_NB, 256, 0, stream>>>(hm, bsum, HM_N);
    scan_k2<<<1, 1024, 0, stream>>>(bsum, HM_NB);
    scan_k3<<<HM_NB, 256, 0, stream>>>(hm, bsum, HM_N);
    binoff_kernel<<<1, 256, 0, stream>>>(hm, binoff);
    bucket2_kernel<<<NBLK, 256, 0, stream>>>(src, dst, etype, hm, bucket);
    place_kernel<<<NBINS, 256, 0, stream>>>(bucket, binoff, cs, rec);

    wt_convert<<<N_RELS + 1, 256, 0, stream>>>(W1, root1, Wt);
    wt2_convert<<<(11 * 32 * 32 + 255) / 256, 256, 0, stream>>>(W2, root2, W2t);

    xform_gemm<<<(N_NODES + 63) / 64, 256, 0, stream>>>(x, Wt, b1, h1, agg1);

    conv1_agg<<<(N_NODES + 31) / 32, 256, 0, stream>>>(h1, rec, cs, agg1, st1);
    bn_relu1<<<(N_NODES * HID + 255) / 256, 256, 0, stream>>>(agg1, st1, gamma1, beta1, hbnb);

    conv2_agg<<<(N_CELLS + 127) / 128, 256, 0, stream>>>(hbnb, rec, cs, agg2);
    gemm2<<<(N_NODES + 63) / 64, 256, 0, stream>>>(agg2, W2t, b2, buf2);
    bn_stats<N_CLASSES><<<512, 256, 0, stream>>>(buf2, st2);
    final_kernel<<<(N_NODES * N_CLASSES + 255) / 256, 256, 0, stream>>>(buf2, st2, gamma2, beta2, out);
}

// Round 17
// 313.854 us; speedup vs baseline: 1.1615x; 1.1615x over previous
//
#include <hip/hip_runtime.h>
#include <hip/hip_bf16.h>

#define N_NODES 100000
#define N_EDGES 3200000
#define F_IN 128
#define HID 16
#define N_CLASSES 32
#define N_RELS 20
#define BN_EPS 1e-5f
#define N_CELLS (N_NODES * N_RELS)          // 2,000,000  (REL-MAJOR: m = r*N_NODES + d)
#define BIN_SHIFT 13
#define BIN_CELLS 8192
#define NBINS ((N_CELLS + BIN_CELLS - 1) / BIN_CELLS)   // 245
#define CHUNK 8192
#define NBLK ((N_EDGES + CHUNK - 1) / CHUNK)            // 391
#define HM_N (NBINS * NBLK)                             // 95,795
#define HM_NB ((HM_N + 2047) / 2048)                    // 47
#define SLOT_ELEMS (N_NODES * HID)                      // 1,600,000 bf16 per slot
#define XPAD 136                                        // padded LDS row stride (bf16)

// ---------------- workspace layout (bytes), peak 98.1 MB ----------------
#define OFF_CS     0ull                 // int[N_CELLS]          8,000,000 (cell end-offsets)
#define OFF_REC    8000000ull           // u32[E] (src)         12,800,000 ; overlaid by buf2 after conv2_agg
#define OFF_AGG1   20800000ull          // float[N*16]           6,400,000
#define OFF_HM     27200000ull          // int[HM_N]               384,000 (rounded)
#define OFF_BSUM   27584000ull          // int[1024]                 4,096
#define OFF_BINOFF 27588096ull          // int[NBINS+1]              1,024
#define OFF_ST1    27589120ull          // float[64]                   256
#define OFF_ST2    27589376ull          // float[64]                   256
#define OFF_WT     27589632ull          // bf16[21*4*64*8] fragment-major  86,016
#define OFF_W2T    27675648ull          // bf16[11*32*32]           22,528
#define OFF_X      27698176ull          // bf16 regionX: 22 slots x [N*16] = 70,400,000 -> 98,098,176
                                        // CSR build: u32 bucket[E] (12.8 MB) overlays slots 0..3.
                                        // xform: slots 0..19 = h1; slot 20 = hbnb; slot 21 unused (finite).
                                        // conv2: agg2 view = slots 0..21; buf2 overlays rec after conv2_agg.
#define SLOT_BYTES 3200000ull           // one [N][16] bf16 slot

typedef __attribute__((ext_vector_type(8))) short bf16x8;
typedef __attribute__((ext_vector_type(4))) short bf16x4;
typedef __attribute__((ext_vector_type(4))) float f32x4;

__device__ inline short f2bf(float f) {
    union { __hip_bfloat16 h; short s; } u;
    u.h = __float2bfloat16(f);
    return u.s;
}

__device__ inline float bf2f(short s) {
    union { unsigned u; float f; } x;
    x.u = ((unsigned)(unsigned short)s) << 16;
    return x.f;
}

// ---------------- CSR build: hist2 -> scan(hm) -> binoff -> bucket2 -> place ----------------

__global__ __launch_bounds__(256) void hist2_kernel(const int* __restrict__ et,
                                                    const int* __restrict__ dst,
                                                    int* __restrict__ hm) {
    __shared__ int lh[NBINS];
    int t = threadIdx.x;
    for (int i = t; i < NBINS; i += 256) lh[i] = 0;
    __syncthreads();
    int e0 = blockIdx.x * CHUNK, e1 = min(e0 + CHUNK, N_EDGES);
    for (int e = e0 + t; e < e1; e += 256) {
        int m = et[e] * N_NODES + dst[e];
        atomicAdd(&lh[m >> BIN_SHIFT], 1);
    }
    __syncthreads();
    for (int i = t; i < NBINS; i += 256) hm[i * NBLK + blockIdx.x] = lh[i];
}

__global__ void scan_k1(const int* __restrict__ a, int* __restrict__ bsum, int n) {
    __shared__ int red[256];
    int base = blockIdx.x * 2048 + threadIdx.x * 8;
    int s = 0;
#pragma unroll
    for (int i = 0; i < 8; ++i) {
        int idx = base + i;
        if (idx < n) s += a[idx];
    }
    red[threadIdx.x] = s;
    __syncthreads();
    for (int off = 128; off > 0; off >>= 1) {
        if (threadIdx.x < off) red[threadIdx.x] += red[threadIdx.x + off];
        __syncthreads();
    }
    if (threadIdx.x == 0) bsum[blockIdx.x] = red[0];
}

__global__ void scan_k2(int* __restrict__ bsum, int nb) {
    __shared__ int p[1024];
    int t = threadIdx.x;
    int v = (t < nb) ? bsum[t] : 0;
    p[t] = v;
    __syncthreads();
    for (int off = 1; off < 1024; off <<= 1) {
        int a = (t >= off) ? p[t - off] : 0;
        __syncthreads();
        p[t] += a;
        __syncthreads();
    }
    if (t < nb) bsum[t] = p[t] - v;  // exclusive
}

__global__ void scan_k3(int* __restrict__ a, const int* __restrict__ bsum, int n) {
    __shared__ int red[256];
    int base = blockIdx.x * 2048 + threadIdx.x * 8;
    int v[8];
    int s = 0;
#pragma unroll
    for (int i = 0; i < 8; ++i) {
        int idx = base + i;
        v[i] = (idx < n) ? a[idx] : 0;
        s += v[i];
    }
    red[threadIdx.x] = s;
    __syncthreads();
    for (int off = 1; off < 256; off <<= 1) {
        int t = (threadIdx.x >= off) ? red[threadIdx.x - off] : 0;
        __syncthreads();
        red[threadIdx.x] += t;
        __syncthreads();
    }
    int run = bsum[blockIdx.x] + red[threadIdx.x] - s;  // exclusive
#pragma unroll
    for (int i = 0; i < 8; ++i) {
        int idx = base + i;
        if (idx < n) a[idx] = run;
        run += v[i];
    }
}

__global__ void binoff_kernel(const int* __restrict__ hm, int* __restrict__ binoff) {
    int t = threadIdx.x;  // 256 >= NBINS
    if (t < NBINS) binoff[t] = hm[t * NBLK];
    if (t == 0) binoff[NBINS] = N_EDGES;
}

// deterministic partition; u32 payload: (cell_within_bin << 17) | src
__global__ __launch_bounds__(256) void bucket2_kernel(const int* __restrict__ src,
                                                      const int* __restrict__ dst,
                                                      const int* __restrict__ et,
                                                      const int* __restrict__ hm,
                                                      unsigned* __restrict__ bucket) {
    __shared__ int ptr[NBINS];
    int t = threadIdx.x;
    for (int i = t; i < NBINS; i += 256) ptr[i] = hm[i * NBLK + blockIdx.x];
    __syncthreads();
    int e0 = blockIdx.x * CHUNK, e1 = min(e0 + CHUNK, N_EDGES);
    for (int e = e0 + t; e < e1; e += 256) {
        int m = et[e] * N_NODES + dst[e];
        int pos = atomicAdd(&ptr[m >> BIN_SHIFT], 1);
        bucket[pos] = ((unsigned)(m & (BIN_CELLS - 1)) << 17) | (unsigned)src[e];
    }
}

// one workgroup per bin: cell hist + scan + placement entirely in LDS
__global__ __launch_bounds__(256) void place_kernel(const unsigned* __restrict__ bucket,
                                                    const int* __restrict__ binoff,
                                                    int* __restrict__ cs,
                                                    unsigned* __restrict__ rec) {
    __shared__ int cnt[BIN_CELLS];
    __shared__ int part[256];
    int b = blockIdx.x;
    int cellbase = b << BIN_SHIFT;
    int ncells = min(BIN_CELLS, N_CELLS - cellbase);
    int ebase = binoff[b], eend = binoff[b + 1];
    int t = threadIdx.x;
    for (int i = t; i < BIN_CELLS; i += 256) cnt[i] = 0;
    __syncthreads();
    for (int e = ebase + t; e < eend; e += 256) {
        int c = (int)(bucket[e] >> 17);
        atomicAdd(&cnt[c], 1);
    }
    __syncthreads();
    int b32 = t * 32;
    int s = 0;
#pragma unroll
    for (int i = 0; i < 32; ++i) s += cnt[b32 + i];
    part[t] = s;
    __syncthreads();
    for (int off = 1; off < 256; off <<= 1) {
        int a = (t >= off) ? part[t - off] : 0;
        __syncthreads();
        part[t] += a;
        __syncthreads();
    }
    int run = (t ? part[t - 1] : 0);
#pragma unroll
    for (int i = 0; i < 32; ++i) { int c = cnt[b32 + i]; cnt[b32 + i] = run; run += c; }
    __syncthreads();
    for (int e = ebase + t; e < eend; e += 256) {
        unsigned p = bucket[e];
        int c = (int)(p >> 17);
        int pos = ebase + atomicAdd(&cnt[c], 1);
        rec[pos] = p & 0x1FFFFu;
    }
    __syncthreads();
    for (int c = t; c < ncells; c += 256) cs[cellbase + c] = ebase + cnt[c];
}

// ---------------- weight prep ----------------

// FRAGMENT-MAJOR: WtF[(r*4+s)*64 + kgrp*16 + col][8] = W_r[s*32+kgrp*8+e][col]
__global__ void wt_convert(const float* __restrict__ W1, const float* __restrict__ root1,
                           __hip_bfloat16* __restrict__ Wt) {
    int r = blockIdx.x;  // 0..20
    const float* src = (r < N_RELS) ? (W1 + (size_t)r * F_IN * HID) : root1;
    for (int i = threadIdx.x; i < F_IN * HID; i += 256) {
        int f = i >> 4, o = i & 15;
        int s = f >> 5, kgrp = (f >> 3) & 3, e = f & 7;
        size_t dst = (((size_t)(r * 4 + s) * 64) + kgrp * 16 + o) * 8 + e;
        Wt[dst] = __float2bfloat16(src[i]);
    }
}

__global__ void wt2_convert(const float* __restrict__ W2, const float* __restrict__ root2,
                            __hip_bfloat16* __restrict__ W2t) {
    int i = blockIdx.x * 256 + threadIdx.x;  // over 11*32*32
    if (i < 11 * 32 * 32) {
        int p = i >> 10, oc = (i >> 5) & 31, k = i & 31;
        float v;
        if (p == 10) v = (k < 16) ? root2[k * N_CLASSES + oc] : 0.f;
        else v = W2[((size_t)(2 * p + (k >> 4)) * HID + (k & 15)) * N_CLASSES + oc];
        W2t[i] = __float2bfloat16(v);
    }
}

// ---------------- conv1 ----------------

__global__ __launch_bounds__(256, 4) void xform_gemm(const float* __restrict__ x,
                                                     const __hip_bfloat16* __restrict__ Wt,
                                                     const float* __restrict__ b1,
                                                     __hip_bfloat16* __restrict__ h1,
                                                     float* __restrict__ agg1) {
    __shared__ __hip_bfloat16 xs[64 * XPAD];   // 17,408 B
    int t = threadIdx.x;
    int nodeBase = blockIdx.x * 64;

#pragma unroll
    for (int it = 0; it < 4; ++it) {
        int idx = it * 256 + t;
        int ln = idx >> 4;
        int g = (idx & 15) * 8;
        int node = nodeBase + ln;
        float4 a = {0.f, 0.f, 0.f, 0.f}, b = {0.f, 0.f, 0.f, 0.f};
        if (node < N_NODES) {
            const float* xp = x + (size_t)node * F_IN + g;
            a = *(const float4*)xp;
            b = *(const float4*)(xp + 4);
        }
        bf16x8 v;
        v[0] = f2bf(a.x); v[1] = f2bf(a.y); v[2] = f2bf(a.z); v[3] = f2bf(a.w);
        v[4] = f2bf(b.x); v[5] = f2bf(b.y); v[6] = f2bf(b.z); v[7] = f2bf(b.w);
        *(bf16x8*)(&xs[ln * XPAD + g]) = v;
    }
    __syncthreads();

    int lane = t & 63;
    int wave = t >> 6;
    int col = lane & 15;
    int kgrp = lane >> 4;
    int row = wave * 16 + col;
    int node = nodeBase + row;
    bool valid = node < N_NODES;

    bf16x8 xf[4];
#pragma unroll
    for (int s = 0; s < 4; ++s)
        xf[s] = *(const bf16x8*)(&xs[row * XPAD + s * 32 + kgrp * 8]);

    for (int r = 0; r < N_RELS + 1; ++r) {
        f32x4 acc = {0.f, 0.f, 0.f, 0.f};
#pragma unroll
        for (int s = 0; s < 4; ++s) {
            bf16x8 wf = *(const bf16x8*)(Wt + (((size_t)(r * 4 + s) * 64) + lane) * 8);
            acc = __builtin_amdgcn_mfma_f32_16x16x32_bf16(wf, xf[s], acc, 0, 0, 0);
        }
        if (valid) {
            if (r < N_RELS) {
                union { ushort4 u4; short s4[4]; } o;
                o.s4[0] = f2bf(acc[0]); o.s4[1] = f2bf(acc[1]);
                o.s4[2] = f2bf(acc[2]); o.s4[3] = f2bf(acc[3]);
                *(ushort4*)(h1 + ((size_t)r * N_NODES + node) * HID + kgrp * 4) = o.u4;
            } else {
                int c0 = kgrp * 4;
                float4 o = {acc[0] + b1[c0], acc[1] + b1[c0 + 1],
                            acc[2] + b1[c0 + 2], acc[3] + b1[c0 + 3]};
                *(float4*)(agg1 + (size_t)node * HID + c0) = o;
            }
        }
    }
}

// 4 lanes per dst; rels processed in batches of 4 with cs pointer-pairs
// preloaded (8 independent loads issued together) so the per-rel dependent
// chain is only rec->gather, software-pipelineable across the batch.
__global__ __launch_bounds__(256) void conv1_agg(const __hip_bfloat16* __restrict__ h1,
                                                 const unsigned* __restrict__ rec,
                                                 const int* __restrict__ cs,
                                                 float* __restrict__ agg1,
                                                 float* __restrict__ st1) {
    __shared__ float ls[HID], lq[HID];
    if (threadIdx.x < HID) { ls[threadIdx.x] = 0.f; lq[threadIdx.x] = 0.f; }
    __syncthreads();
    int q = threadIdx.x & 3, slot = threadIdx.x >> 2;
    int d = blockIdx.x * 64 + slot;
    bool valid = d < N_NODES;
    int dd = valid ? d : 0;
    float acc[4] = {0.f, 0.f, 0.f, 0.f};

    for (int rb = 0; rb < N_RELS; rb += 4) {
        int s0v[4], s1v[4];
#pragma unroll
        for (int j = 0; j < 4; ++j) {
            int m = (rb + j) * N_NODES + dd;
            s0v[j] = (m == 0) ? 0 : cs[m - 1];
            s1v[j] = cs[m];
        }
#pragma unroll
        for (int j = 0; j < 4; ++j) {
            int s0 = s0v[j], s1 = s1v[j];
            if (s1 > s0) {
                const __hip_bfloat16* hr = h1 + (size_t)(rb + j) * SLOT_ELEMS + q * 4;
                float pa[4] = {0.f, 0.f, 0.f, 0.f};
                for (int i = s0; i < s1; ++i) {
                    int sn = rec[i];
                    bf16x4 v = *(const bf16x4*)(hr + (size_t)sn * HID);
#pragma unroll
                    for (int k = 0; k < 4; ++k) pa[k] += bf2f(v[k]);
                }
                float inv = 1.0f / (float)(s1 - s0);
#pragma unroll
                for (int k = 0; k < 4; ++k) acc[k] = fmaf(pa[k], inv, acc[k]);
            }
        }
    }

    float vout[4] = {0.f, 0.f, 0.f, 0.f};
    if (valid) {
        float4* ap = (float4*)(agg1 + (size_t)d * HID + q * 4);
        float4 a0 = *ap;
        vout[0] = a0.x + acc[0]; vout[1] = a0.y + acc[1];
        vout[2] = a0.z + acc[2]; vout[3] = a0.w + acc[3];
        *ap = float4{vout[0], vout[1], vout[2], vout[3]};
    }
#pragma unroll
    for (int k = 0; k < 4; ++k) {
        atomicAdd(&ls[q * 4 + k], vout[k]);
        atomicAdd(&lq[q * 4 + k], vout[k] * vout[k]);
    }
    __syncthreads();
    if (threadIdx.x < HID) {
        atomicAdd(&st1[threadIdx.x], ls[threadIdx.x]);
        atomicAdd(&st1[HID + threadIdx.x], lq[threadIdx.x]);
    }
}

// BN1 + ReLU -> bf16 into regionX slot 20
__global__ void bn_relu1(const float* __restrict__ a, const float* __restrict__ stats,
                         const float* __restrict__ gamma, const float* __restrict__ beta,
                         __hip_bfloat16* __restrict__ hb) {
    int i = blockIdx.x * 256 + threadIdx.x;
    if (i < N_NODES * HID) {
        int j = i & (HID - 1);
        float mean = stats[j] * (1.0f / N_NODES);
        float var = stats[HID + j] * (1.0f / N_NODES) - mean * mean;
        float rs = rsqrtf(var + BN_EPS);
        float val = (a[i] - mean) * rs * gamma[j] + beta[j];
        hb[i] = __float2bfloat16(fmaxf(val, 0.f));
    }
}

// ---------------- conv2 ----------------

// 2 lanes per cell, linear grid over cells; hbn (3.2 MB) L2-resident;
// bf16x8 gathers; coalesced bf16x8 mean writes; no atomics.
__global__ __launch_bounds__(256) void conv2_agg(const __hip_bfloat16* __restrict__ hbnb,
                                                 const unsigned* __restrict__ rec,
                                                 const int* __restrict__ cs,
                                                 __hip_bfloat16* __restrict__ agg2) {
    int pair = threadIdx.x >> 1, half = threadIdx.x & 1;
    int m = blockIdx.x * 128 + pair;
    if (m >= N_CELLS) return;
    int s0 = (m == 0) ? 0 : cs[m - 1];
    int s1 = cs[m];
    const __hip_bfloat16* hb = hbnb + half * 8;
    float acc[8] = {0.f, 0.f, 0.f, 0.f, 0.f, 0.f, 0.f, 0.f};
    for (int i = s0; i < s1; ++i) {
        int sn = rec[i];
        bf16x8 v = *(const bf16x8*)(hb + (size_t)sn * HID);
#pragma unroll
        for (int k = 0; k < 8; ++k) acc[k] += bf2f(v[k]);
    }
    float inv = (s1 > s0) ? 1.0f / (float)(s1 - s0) : 0.f;
    bf16x8 o;
#pragma unroll
    for (int k = 0; k < 8; ++k) o[k] = f2bf(acc[k] * inv);
    *(bf16x8*)(agg2 + (size_t)m * HID + half * 8) = o;
}

// buf2[n][c] = sum_p mfma over relation pairs (+ root2 via slot 20) + b2
__global__ __launch_bounds__(256) void gemm2(const __hip_bfloat16* __restrict__ agg2,
                                             const __hip_bfloat16* __restrict__ W2t,
                                             const float* __restrict__ b2,
                                             float* __restrict__ buf2) {
    int wave = threadIdx.x >> 6, lane = threadIdx.x & 63;
    int col = lane & 15, kgrp = lane >> 4;
    int node = blockIdx.x * 64 + wave * 16 + col;
    bool valid = node < N_NODES;
    int nidx = valid ? node : 0;

    bf16x8 bf[11];
#pragma unroll
    for (int p = 0; p < 11; ++p) {
        int slot = 2 * p + (kgrp >> 1);
        bf[p] = *(const bf16x8*)(agg2 + ((size_t)slot * N_NODES + nidx) * HID + (kgrp & 1) * 8);
    }
#pragma unroll
    for (int ct = 0; ct < 2; ++ct) {
        f32x4 acc = {0.f, 0.f, 0.f, 0.f};
#pragma unroll
        for (int p = 0; p < 11; ++p) {
            bf16x8 wf = *(const bf16x8*)(W2t + ((size_t)p * 32 + ct * 16 + col) * 32 + kgrp * 8);
            acc = __builtin_amdgcn_mfma_f32_16x16x32_bf16(wf, bf[p], acc, 0, 0, 0);
        }
        if (valid) {
            int c0 = ct * 16 + kgrp * 4;
            float4 o = {acc[0] + b2[c0], acc[1] + b2[c0 + 1],
                        acc[2] + b2[c0 + 2], acc[3] + b2[c0 + 3]};
            *(float4*)(buf2 + (size_t)node * N_CLASSES + c0) = o;
        }
    }
}

template <int CH>
__global__ void bn_stats(const float* __restrict__ v, float* __restrict__ stats) {
    __shared__ float ls[CH], lq[CH];
    if (threadIdx.x < CH) { ls[threadIdx.x] = 0.f; lq[threadIdx.x] = 0.f; }
    __syncthreads();
    const int total = N_NODES * CH;
    int j = threadIdx.x % CH;
    float s = 0.f, q = 0.f;
    for (int i = blockIdx.x * blockDim.x + threadIdx.x; i < total; i += gridDim.x * blockDim.x) {
        float t = v[i];
        s += t; q += t * t;
    }
    atomicAdd(&ls[j], s);
    atomicAdd(&lq[j], q);
    __syncthreads();
    if (threadIdx.x < CH) {
        atomicAdd(&stats[threadIdx.x], ls[threadIdx.x]);
        atomicAdd(&stats[CH + threadIdx.x], lq[threadIdx.x]);
    }
}

__global__ void final_kernel(const float* __restrict__ buf2, const float* __restrict__ stats,
                             const float* __restrict__ gamma, const float* __restrict__ beta,
                             float* __restrict__ out) {
    int idx = blockIdx.x * 256 + threadIdx.x;  // over N*32, exact
    int j = threadIdx.x & 31;
    float mean = stats[j] * (1.0f / N_NODES);
    float var = stats[N_CLASSES + j] * (1.0f / N_NODES) - mean * mean;
    float rs = rsqrtf(var + BN_EPS);
    float v = fmaxf((buf2[idx] - mean) * rs * gamma[j] + beta[j], 0.f);
    float m = v;
#pragma unroll
    for (int o = 16; o >= 1; o >>= 1) m = fmaxf(m, __shfl_xor(m, o, 32));
    float ex = __expf(v - m);
    float ssum = ex;
#pragma unroll
    for (int o = 16; o >= 1; o >>= 1) ssum += __shfl_xor(ssum, o, 32);
    out[idx] = (v - m) - logf(ssum);
}

// ---------------- launcher ----------------
extern "C" void kernel_launch(void* const* d_in, const int* in_sizes, int n_in,
                              void* d_out, int out_size, void* d_ws, size_t ws_size,
                              hipStream_t stream) {
    const float* x      = (const float*)d_in[0];
    const int*   eidx   = (const int*)d_in[1];
    const int*   etype  = (const int*)d_in[2];
    const float* W1     = (const float*)d_in[3];
    const float* root1  = (const float*)d_in[4];
    const float* b1     = (const float*)d_in[5];
    const float* gamma1 = (const float*)d_in[6];
    const float* beta1  = (const float*)d_in[7];
    const float* W2     = (const float*)d_in[8];
    const float* root2  = (const float*)d_in[9];
    const float* b2     = (const float*)d_in[10];
    const float* gamma2 = (const float*)d_in[11];
    const float* beta2  = (const float*)d_in[12];

    const int* src = eidx;
    const int* dst = eidx + N_EDGES;

    char* ws = (char*)d_ws;
    int*      cs     = (int*)(ws + OFF_CS);
    unsigned* rec    = (unsigned*)(ws + OFF_REC);
    float*    buf2   = (float*)(ws + OFF_REC);     // overlays rec (dead after conv2_agg)
    float*    agg1   = (float*)(ws + OFF_AGG1);
    int*      hm     = (int*)(ws + OFF_HM);
    int*      bsum   = (int*)(ws + OFF_BSUM);
    int*      binoff = (int*)(ws + OFF_BINOFF);
    float*    st1    = (float*)(ws + OFF_ST1);
    float*    st2    = (float*)(ws + OFF_ST2);
    __hip_bfloat16* Wt  = (__hip_bfloat16*)(ws + OFF_WT);
    __hip_bfloat16* W2t = (__hip_bfloat16*)(ws + OFF_W2T);
    unsigned* bucket = (unsigned*)(ws + OFF_X);                                // dead after place_kernel
    __hip_bfloat16* rx   = (__hip_bfloat16*)(ws + OFF_X);                      // regionX base
    __hip_bfloat16* h1   = rx;                                                 // slots 0..19
    __hip_bfloat16* hbnb = rx + (size_t)20 * SLOT_ELEMS;                       // slot 20
    __hip_bfloat16* agg2 = rx;                                                 // slots 0..21 (conv2 view)

    float* out = (float*)d_out;

    hipMemsetAsync(st1, 0, 512, stream);           // zeroes st1 (256B) + st2 (256B)

    hist2_kernel<<<NBLK, 256, 0, stream>>>(etype, dst, hm);
    scan_k1<<<HM_NB, 256, 0, stream>>>(hm, bsum, HM_N);
    scan_k2<<<1, 1024, 0, stream>>>(bsum, HM_NB);
    scan_k3<<<HM_NB, 256, 0, stream>>>(hm, bsum, HM_N);
    binoff_kernel<<<1, 256, 0, stream>>>(hm, binoff);
    bucket2_kernel<<<NBLK, 256, 0, stream>>>(src, dst, etype, hm, bucket);
    place_kernel<<<NBINS, 256, 0, stream>>>(bucket, binoff, cs, rec);

    wt_convert<<<N_RELS + 1, 256, 0, stream>>>(W1, root1, Wt);
    wt2_convert<<<(11 * 32 * 32 + 255) / 256, 256, 0, stream>>>(W2, root2, W2t);

    xform_gemm<<<(N_NODES + 63) / 64, 256, 0, stream>>>(x, Wt, b1, h1, agg1);

    conv1_agg<<<(N_NODES + 63) / 64, 256, 0, stream>>>(h1, rec, cs, agg1, st1);
    bn_relu1<<<(N_NODES * HID + 255) / 256, 256, 0, stream>>>(agg1, st1, gamma1, beta1, hbnb);

    conv2_agg<<<(N_CELLS + 127) / 128, 256, 0, stream>>>(hbnb, rec, cs, agg2);
    gemm2<<<(N_NODES + 63) / 64, 256, 0, stream>>>(agg2, W2t, b2, buf2);
    bn_stats<N_CLASSES><<<512, 256, 0, stream>>>(buf2, st2);
    final_kernel<<<(N_NODES * N_CLASSES + 255) / 256, 256, 0, stream>>>(buf2, st2, gamma2, beta2, out);
}